// Round 3
// baseline (448.232 us; speedup 1.0000x reference)
//
#include <hip/hip_runtime.h>
#include <math.h>

// HashGrid: 8 LODs, hashed trilinear interp, 1 feature/entry, summed over LODs.
// LODS  = [17, 27, 44, 71, 116, 191, 313, res7(host-computed, 512 or 513)]
// SIZES = [4913, 19683, 85184, 357911, 2^19, 2^19, 2^19, 2^19]
// codebook layout: [8][524288][1] float32.
//
// R3 strategy (on top of R2's bf16 LDS/L2 tables):
//  - Batch gathers: compute 16 indices (2 LODs) and issue all 16 loads before
//    consuming any; overlap next batch's address math + the LDS LODs with
//    in-flight loads. Goal: ~16-32 outstanding gathers/wave vs ~6 at VGPR=32.

static constexpr unsigned CB_STRIDE = 524288u;
static constexpr int S0 = 4913;    // 17^3
static constexpr int S1 = 19683;   // 27^3
// ws (bf16) element offsets for LOD2..7
static constexpr int WO2 = 0;        // 85184
static constexpr int WO3 = 85184;    // 357911
static constexpr int WO4 = 443104;   // 524288
static constexpr int WO5 = 967392;
static constexpr int WO6 = 1491680;
static constexpr int WO7 = 2015968;
static constexpr size_t WS_NEED_BYTES = 2540256u * 2u;  // 5.08 MB

__device__ __forceinline__ unsigned short f32_to_bf16_rne(float f) {
    unsigned u = __float_as_uint(f);
    u = (u + 0x7FFFu + ((u >> 16) & 1u)) >> 16;
    return (unsigned short)u;
}
__device__ __forceinline__ float bf16_to_f32(unsigned short s) {
    return __uint_as_float(((unsigned)s) << 16);
}

struct F3 { float x, y, z; };

template <unsigned SIZE, bool POW2>
__device__ __forceinline__ void idx8(float p01x, float p01y, float p01z, int res,
                                     unsigned o[8], F3& fr)
{
    const float rm1 = (float)(res - 1);
    float xx = p01x * rm1, yy = p01y * rm1, zz = p01z * rm1;
    float fx = floorf(xx), fy = floorf(yy), fz = floorf(zz);
    const float cmax = (float)(res - 2);
    fx = fminf(fmaxf(fx, 0.0f), cmax);
    fy = fminf(fmaxf(fy, 0.0f), cmax);
    fz = fminf(fmaxf(fz, 0.0f), cmax);
    fr.x = xx - fx; fr.y = yy - fy; fr.z = zz - fz;
    const unsigned ix = (unsigned)(int)fx;
    const unsigned iy = (unsigned)(int)fy;
    const unsigned iz = (unsigned)(int)fz;

    const unsigned hx0 = ix;                  // PRIME0 = 1
    const unsigned hx1 = ix + 1u;
    const unsigned hy0 = iy * 2654435761u;
    const unsigned hy1 = hy0 + 2654435761u;
    const unsigned hz0 = iz * 805459861u;
    const unsigned hz1 = hz0 + 805459861u;

    unsigned v0 = hx0 ^ hy0 ^ hz0;
    unsigned v1 = hx0 ^ hy0 ^ hz1;
    unsigned v2 = hx0 ^ hy1 ^ hz0;
    unsigned v3 = hx0 ^ hy1 ^ hz1;
    unsigned v4 = hx1 ^ hy0 ^ hz0;
    unsigned v5 = hx1 ^ hy0 ^ hz1;
    unsigned v6 = hx1 ^ hy1 ^ hz0;
    unsigned v7 = hx1 ^ hy1 ^ hz1;

    if (POW2) {
        const unsigned m = SIZE - 1u;
        v0 &= m; v1 &= m; v2 &= m; v3 &= m; v4 &= m; v5 &= m; v6 &= m; v7 &= m;
    } else {
        v0 %= SIZE; v1 %= SIZE; v2 %= SIZE; v3 %= SIZE;
        v4 %= SIZE; v5 %= SIZE; v6 %= SIZE; v7 %= SIZE;
    }
    o[0] = v0; o[1] = v1; o[2] = v2; o[3] = v3;
    o[4] = v4; o[5] = v5; o[6] = v6; o[7] = v7;
}

__device__ __forceinline__ void load8(const unsigned short* __restrict__ t,
                                      const unsigned o[8], unsigned short r[8])
{
#pragma unroll
    for (int k = 0; k < 8; ++k) r[k] = t[o[k]];
}

__device__ __forceinline__ float acc8(const unsigned short r[8], F3 fr)
{
    const float wx1 = fr.x, wx0 = 1.0f - fr.x;
    const float wy1 = fr.y, wy0 = 1.0f - fr.y;
    const float wz1 = fr.z, wz0 = 1.0f - fr.z;
    const float w00 = wy0 * wz0, w01 = wy0 * wz1;
    const float w10 = wy1 * wz0, w11 = wy1 * wz1;
    const float sx0 = bf16_to_f32(r[0]) * w00 + bf16_to_f32(r[1]) * w01
                    + bf16_to_f32(r[2]) * w10 + bf16_to_f32(r[3]) * w11;
    const float sx1 = bf16_to_f32(r[4]) * w00 + bf16_to_f32(r[5]) * w01
                    + bf16_to_f32(r[6]) * w10 + bf16_to_f32(r[7]) * w11;
    return wx0 * sx0 + wx1 * sx1;
}

// prep: convert LOD2..7 table prefixes to bf16 in ws
__global__ __launch_bounds__(1024)
void HashGrid_convert_kernel(const float* __restrict__ codebook,
                             unsigned short* __restrict__ ws)
{
    const int lod = blockIdx.y;  // 0..5 -> LOD2..7
    const int sizes[6] = {85184, 357911, 524288, 524288, 524288, 524288};
    const int offs[6]  = {WO2, WO3, WO4, WO5, WO6, WO7};
    const int idx = blockIdx.x * 1024 + threadIdx.x;
    if (idx < sizes[lod])
        ws[offs[lod] + idx] = f32_to_bf16_rne(codebook[(unsigned)(lod + 2) * CB_STRIDE + idx]);
}

__global__ __launch_bounds__(1024, 8)
void HashGrid_88278757802387_kernel(const float* __restrict__ pts,
                                    const float* __restrict__ codebook,
                                    const unsigned short* __restrict__ ws,
                                    float* __restrict__ out,
                                    int n, int res7)
{
    __shared__ unsigned short sm[S0 + S1];  // 49.2 KB -> 2 blocks/CU
    for (int j = threadIdx.x; j < S0 + S1; j += 1024)
        sm[j] = f32_to_bf16_rne(j < S0 ? codebook[j] : codebook[CB_STRIDE + (j - S0)]);
    __syncthreads();

    const int i = blockIdx.x * 1024 + threadIdx.x;
    if (i >= n) return;

    const float p01x = pts[3 * i + 0] * 0.5f + 0.5f;
    const float p01y = pts[3 * i + 1] * 0.5f + 0.5f;
    const float p01z = pts[3 * i + 2] * 0.5f + 0.5f;

    // ---- batch A: LOD2 + LOD3 -> issue 16 loads ----
    unsigned oA0[8], oA1[8]; F3 fA0, fA1;
    idx8<85184u,  false>(p01x, p01y, p01z, 44, oA0, fA0);
    idx8<357911u, false>(p01x, p01y, p01z, 71, oA1, fA1);
    unsigned short rA0[8], rA1[8];
    load8(ws + WO2, oA0, rA0);
    load8(ws + WO3, oA1, rA1);

    // ---- batch B: LOD4 + LOD5 -> issue 16 loads (A in flight) ----
    unsigned oB0[8], oB1[8]; F3 fB0, fB1;
    idx8<524288u, true>(p01x, p01y, p01z, 116, oB0, fB0);
    idx8<524288u, true>(p01x, p01y, p01z, 191, oB1, fB1);
    unsigned short rB0[8], rB1[8];
    load8(ws + WO4, oB0, rB0);
    load8(ws + WO5, oB1, rB1);

    // ---- LDS LODs 0/1 (overlaps global latency) ----
    unsigned oL0[8], oL1[8]; F3 fL0, fL1;
    idx8<4913u,  false>(p01x, p01y, p01z, 17, oL0, fL0);
    idx8<19683u, false>(p01x, p01y, p01z, 27, oL1, fL1);
    unsigned short rL0[8], rL1[8];
    load8(sm, oL0, rL0);
    load8(sm + S0, oL1, rL1);
    float acc = acc8(rL0, fL0) + acc8(rL1, fL1);

    // ---- consume A, issue C: LOD6 + LOD7 ----
    acc += acc8(rA0, fA0) + acc8(rA1, fA1);
    unsigned oC0[8], oC1[8]; F3 fC0, fC1;
    idx8<524288u, true>(p01x, p01y, p01z, 313, oC0, fC0);
    idx8<524288u, true>(p01x, p01y, p01z, res7, oC1, fC1);
    unsigned short rC0[8], rC1[8];
    load8(ws + WO6, oC0, rC0);
    load8(ws + WO7, oC1, rC1);

    // ---- consume B, then C ----
    acc += acc8(rB0, fB0) + acc8(rB1, fB1);
    acc += acc8(rC0, fC0) + acc8(rC1, fC1);

    out[i] = acc;
}

// fallback (no ws): original per-LOD f32 path
__global__ __launch_bounds__(1024, 4)
void HashGrid_fallback_kernel(const float* __restrict__ pts,
                              const float* __restrict__ codebook,
                              float* __restrict__ out,
                              int n, int res7)
{
    const int i = blockIdx.x * 1024 + threadIdx.x;
    if (i >= n) return;
    const float p01x = pts[3 * i + 0] * 0.5f + 0.5f;
    const float p01y = pts[3 * i + 1] * 0.5f + 0.5f;
    const float p01z = pts[3 * i + 2] * 0.5f + 0.5f;
    float acc = 0.0f;
    const int    reslist[8]  = {17, 27, 44, 71, 116, 191, 313, res7};
    const unsigned sizelist[8] = {4913u, 19683u, 85184u, 357911u, 524288u, 524288u, 524288u, 524288u};
    for (int l = 0; l < 8; ++l) {
        unsigned o[8]; F3 fr;
        const int res = reslist[l];
        const unsigned size = sizelist[l];
        const float rm1 = (float)(res - 1);
        float xx = p01x * rm1, yy = p01y * rm1, zz = p01z * rm1;
        float fx = fminf(fmaxf(floorf(xx), 0.0f), (float)(res - 2));
        float fy = fminf(fmaxf(floorf(yy), 0.0f), (float)(res - 2));
        float fz = fminf(fmaxf(floorf(zz), 0.0f), (float)(res - 2));
        fr.x = xx - fx; fr.y = yy - fy; fr.z = zz - fz;
        const unsigned ix = (unsigned)(int)fx, iy = (unsigned)(int)fy, iz = (unsigned)(int)fz;
        const unsigned hy0 = iy * 2654435761u, hy1 = hy0 + 2654435761u;
        const unsigned hz0 = iz * 805459861u,  hz1 = hz0 + 805459861u;
        o[0] = (ix ^ hy0 ^ hz0) % size;      o[1] = (ix ^ hy0 ^ hz1) % size;
        o[2] = (ix ^ hy1 ^ hz0) % size;      o[3] = (ix ^ hy1 ^ hz1) % size;
        o[4] = ((ix+1u) ^ hy0 ^ hz0) % size; o[5] = ((ix+1u) ^ hy0 ^ hz1) % size;
        o[6] = ((ix+1u) ^ hy1 ^ hz0) % size; o[7] = ((ix+1u) ^ hy1 ^ hz1) % size;
        const float* tab = codebook + (unsigned)l * CB_STRIDE;
        const float wx1 = fr.x, wx0 = 1.0f - fr.x;
        const float wy1 = fr.y, wy0 = 1.0f - fr.y;
        const float wz1 = fr.z, wz0 = 1.0f - fr.z;
        const float w00 = wy0*wz0, w01 = wy0*wz1, w10 = wy1*wz0, w11 = wy1*wz1;
        acc += wx0 * (tab[o[0]]*w00 + tab[o[1]]*w01 + tab[o[2]]*w10 + tab[o[3]]*w11)
             + wx1 * (tab[o[4]]*w00 + tab[o[5]]*w01 + tab[o[6]]*w10 + tab[o[7]]*w11);
    }
    out[i] = acc;
}

extern "C" void kernel_launch(void* const* d_in, const int* in_sizes, int n_in,
                              void* d_out, int out_size, void* d_ws, size_t ws_size,
                              hipStream_t stream)
{
    const float* pts      = (const float*)d_in[0];
    const float* codebook = (const float*)d_in[1];
    float* out            = (float*)d_out;
    const int n = in_sizes[0] / 3;

    // numpy-matching LOD7 resolution (16*b^7 sits ~1e-12 from 512.0)
    const double b = exp((log(512.0) - log(16.0)) / 7.0);
    const int res7 = (int)(1.0 + floor(16.0 * pow(b, 7.0)));

    const bool use_ws = (d_ws != nullptr) && (ws_size >= WS_NEED_BYTES);
    const int blocks = (n + 1023) / 1024;

    if (use_ws) {
        unsigned short* ws = (unsigned short*)d_ws;
        hipLaunchKernelGGL(HashGrid_convert_kernel, dim3(512, 6), dim3(1024),
                           0, stream, codebook, ws);
        hipLaunchKernelGGL(HashGrid_88278757802387_kernel, dim3(blocks), dim3(1024),
                           0, stream, pts, codebook, ws, out, n, res7);
    } else {
        hipLaunchKernelGGL(HashGrid_fallback_kernel, dim3(blocks), dim3(1024),
                           0, stream, pts, codebook, out, n, res7);
    }
}

// Round 4
// 407.766 us; speedup vs baseline: 1.0992x; 1.0992x over previous
//
#include <hip/hip_runtime.h>
#include <math.h>

// HashGrid: 8 LODs, hashed trilinear interp, 1 feature/entry, summed over LODs.
// LODS  = [17, 27, 44, 71, 116, 191, 313, res7(host-computed, 512 or 513)]
// SIZES = [4913, 19683, 85184, 357911, 2^19, 2^19, 2^19, 2^19]
// codebook layout: [8][524288][1] float32.
//
// R4: R3's gather batching, but spill-free. All per-corner state lives in
// named-member structs (SROA-safe; R3's pointer-decayed arrays went to
// scratch: WRITE_SIZE 7.8MB -> 216MB). Steady state ~16-24 outstanding
// global u16 gathers per wave.

static constexpr unsigned CB_STRIDE = 524288u;
static constexpr int S0 = 4913;    // 17^3
static constexpr int S1 = 19683;   // 27^3
// ws (bf16) element offsets for LOD2..7
static constexpr int WO2 = 0;        // 85184
static constexpr int WO3 = 85184;    // 357911
static constexpr int WO4 = 443104;   // 524288 (aligned up)
static constexpr int WO5 = 967392;
static constexpr int WO6 = 1491680;
static constexpr int WO7 = 2015968;
static constexpr size_t WS_NEED_BYTES = 2540256u * 2u;  // 5.08 MB

__device__ __forceinline__ unsigned short f32_to_bf16_rne(float f) {
    unsigned u = __float_as_uint(f);
    u = (u + 0x7FFFu + ((u >> 16) & 1u)) >> 16;
    return (unsigned short)u;
}
__device__ __forceinline__ float bf16_to_f32(unsigned short s) {
    return __uint_as_float(((unsigned)s) << 16);
}

struct I8 { unsigned a0, a1, a2, a3, a4, a5, a6, a7; };
struct R8 { unsigned short v0, v1, v2, v3, v4, v5, v6, v7; };
struct W3 { float x, y, z; };

template <unsigned SIZE, bool POW2>
__device__ __forceinline__ I8 idx8(float p01x, float p01y, float p01z, int res, W3& fr)
{
    const float rm1 = (float)(res - 1);
    float xx = p01x * rm1, yy = p01y * rm1, zz = p01z * rm1;
    const float cmax = (float)(res - 2);
    float fx = fminf(fmaxf(floorf(xx), 0.0f), cmax);
    float fy = fminf(fmaxf(floorf(yy), 0.0f), cmax);
    float fz = fminf(fmaxf(floorf(zz), 0.0f), cmax);
    fr.x = xx - fx; fr.y = yy - fy; fr.z = zz - fz;
    const unsigned ix = (unsigned)(int)fx;
    const unsigned iy = (unsigned)(int)fy;
    const unsigned iz = (unsigned)(int)fz;

    const unsigned hx0 = ix;                  // PRIME0 = 1
    const unsigned hx1 = ix + 1u;
    const unsigned hy0 = iy * 2654435761u;
    const unsigned hy1 = hy0 + 2654435761u;
    const unsigned hz0 = iz * 805459861u;
    const unsigned hz1 = hz0 + 805459861u;

    unsigned v0 = hx0 ^ hy0 ^ hz0;
    unsigned v1 = hx0 ^ hy0 ^ hz1;
    unsigned v2 = hx0 ^ hy1 ^ hz0;
    unsigned v3 = hx0 ^ hy1 ^ hz1;
    unsigned v4 = hx1 ^ hy0 ^ hz0;
    unsigned v5 = hx1 ^ hy0 ^ hz1;
    unsigned v6 = hx1 ^ hy1 ^ hz0;
    unsigned v7 = hx1 ^ hy1 ^ hz1;

    if (POW2) {
        const unsigned m = SIZE - 1u;
        v0 &= m; v1 &= m; v2 &= m; v3 &= m; v4 &= m; v5 &= m; v6 &= m; v7 &= m;
    } else {
        v0 %= SIZE; v1 %= SIZE; v2 %= SIZE; v3 %= SIZE;
        v4 %= SIZE; v5 %= SIZE; v6 %= SIZE; v7 %= SIZE;
    }
    I8 o; o.a0 = v0; o.a1 = v1; o.a2 = v2; o.a3 = v3;
          o.a4 = v4; o.a5 = v5; o.a6 = v6; o.a7 = v7;
    return o;
}

__device__ __forceinline__ R8 gather8(const unsigned short* __restrict__ t, I8 o)
{
    R8 r;
    r.v0 = t[o.a0]; r.v1 = t[o.a1]; r.v2 = t[o.a2]; r.v3 = t[o.a3];
    r.v4 = t[o.a4]; r.v5 = t[o.a5]; r.v6 = t[o.a6]; r.v7 = t[o.a7];
    return r;
}

__device__ __forceinline__ float acc8(R8 r, W3 f)
{
    const float wx1 = f.x, wx0 = 1.0f - f.x;
    const float wy1 = f.y, wy0 = 1.0f - f.y;
    const float wz1 = f.z, wz0 = 1.0f - f.z;
    const float w00 = wy0 * wz0, w01 = wy0 * wz1;
    const float w10 = wy1 * wz0, w11 = wy1 * wz1;
    const float sx0 = bf16_to_f32(r.v0) * w00 + bf16_to_f32(r.v1) * w01
                    + bf16_to_f32(r.v2) * w10 + bf16_to_f32(r.v3) * w11;
    const float sx1 = bf16_to_f32(r.v4) * w00 + bf16_to_f32(r.v5) * w01
                    + bf16_to_f32(r.v6) * w10 + bf16_to_f32(r.v7) * w11;
    return wx0 * sx0 + wx1 * sx1;
}

// prep: convert LOD2..7 table prefixes to bf16 in ws
__global__ __launch_bounds__(1024)
void HashGrid_convert_kernel(const float* __restrict__ codebook,
                             unsigned short* __restrict__ ws)
{
    const int lod = blockIdx.y;  // 0..5 -> LOD2..7
    const int sizes[6] = {85184, 357911, 524288, 524288, 524288, 524288};
    const int offs[6]  = {WO2, WO3, WO4, WO5, WO6, WO7};
    const int idx = blockIdx.x * 1024 + threadIdx.x;
    if (idx < sizes[lod])
        ws[offs[lod] + idx] = f32_to_bf16_rne(codebook[(unsigned)(lod + 2) * CB_STRIDE + idx]);
}

__global__ __launch_bounds__(1024, 8)
void HashGrid_88278757802387_kernel(const float* __restrict__ pts,
                                    const float* __restrict__ codebook,
                                    const unsigned short* __restrict__ ws,
                                    float* __restrict__ out,
                                    int n, int res7)
{
    __shared__ unsigned short sm[S0 + S1];  // 49.2 KB -> 2 blocks/CU
    for (int j = threadIdx.x; j < S0 + S1; j += 1024)
        sm[j] = f32_to_bf16_rne(j < S0 ? codebook[j] : codebook[CB_STRIDE + (j - S0)]);
    __syncthreads();

    const int i = blockIdx.x * 1024 + threadIdx.x;
    if (i >= n) return;

    const float p01x = pts[3 * i + 0] * 0.5f + 0.5f;
    const float p01y = pts[3 * i + 1] * 0.5f + 0.5f;
    const float p01z = pts[3 * i + 2] * 0.5f + 0.5f;

    // issue LOD2+LOD3 (16 outstanding)
    W3 fA, fB, fC, fD, fE, fF, fL0, fL1;
    I8 oA = idx8<85184u,  false>(p01x, p01y, p01z, 44, fA);
    I8 oB = idx8<357911u, false>(p01x, p01y, p01z, 71, fB);
    R8 rA = gather8(ws + WO2, oA);
    R8 rB = gather8(ws + WO3, oB);

    // issue LOD4 (24 outstanding)
    I8 oC = idx8<524288u, true>(p01x, p01y, p01z, 116, fC);
    R8 rC = gather8(ws + WO4, oC);

    // LDS LODs 0/1 under the in-flight global loads
    I8 oL0 = idx8<4913u,  false>(p01x, p01y, p01z, 17, fL0);
    I8 oL1 = idx8<19683u, false>(p01x, p01y, p01z, 27, fL1);
    R8 rL0 = gather8(sm, oL0);
    R8 rL1 = gather8(sm + S0, oL1);
    float acc = acc8(rL0, fL0) + acc8(rL1, fL1);

    // consume A, issue LOD5
    I8 oD = idx8<524288u, true>(p01x, p01y, p01z, 191, fD);
    R8 rD = gather8(ws + WO5, oD);
    acc += acc8(rA, fA);

    // consume B, issue LOD6
    I8 oE = idx8<524288u, true>(p01x, p01y, p01z, 313, fE);
    R8 rE = gather8(ws + WO6, oE);
    acc += acc8(rB, fB);

    // consume C, issue LOD7
    I8 oF = idx8<524288u, true>(p01x, p01y, p01z, res7, fF);
    R8 rF = gather8(ws + WO7, oF);
    acc += acc8(rC, fC);

    // drain
    acc += acc8(rD, fD);
    acc += acc8(rE, fE);
    acc += acc8(rF, fF);

    out[i] = acc;
}

// fallback (no ws): per-LOD f32 path
__global__ __launch_bounds__(1024, 4)
void HashGrid_fallback_kernel(const float* __restrict__ pts,
                              const float* __restrict__ codebook,
                              float* __restrict__ out,
                              int n, int res7)
{
    const int i = blockIdx.x * 1024 + threadIdx.x;
    if (i >= n) return;
    const float p01x = pts[3 * i + 0] * 0.5f + 0.5f;
    const float p01y = pts[3 * i + 1] * 0.5f + 0.5f;
    const float p01z = pts[3 * i + 2] * 0.5f + 0.5f;
    float acc = 0.0f;
    const int      reslist[8]  = {17, 27, 44, 71, 116, 191, 313, res7};
    const unsigned sizelist[8] = {4913u, 19683u, 85184u, 357911u, 524288u, 524288u, 524288u, 524288u};
    for (int l = 0; l < 8; ++l) {
        const int res = reslist[l];
        const unsigned size = sizelist[l];
        const float rm1 = (float)(res - 1);
        float xx = p01x * rm1, yy = p01y * rm1, zz = p01z * rm1;
        float fx = fminf(fmaxf(floorf(xx), 0.0f), (float)(res - 2));
        float fy = fminf(fmaxf(floorf(yy), 0.0f), (float)(res - 2));
        float fz = fminf(fmaxf(floorf(zz), 0.0f), (float)(res - 2));
        const float frx = xx - fx, fry = yy - fy, frz = zz - fz;
        const unsigned ix = (unsigned)(int)fx, iy = (unsigned)(int)fy, iz = (unsigned)(int)fz;
        const unsigned hy0 = iy * 2654435761u, hy1 = hy0 + 2654435761u;
        const unsigned hz0 = iz * 805459861u,  hz1 = hz0 + 805459861u;
        const unsigned o0 = (ix ^ hy0 ^ hz0) % size,      o1 = (ix ^ hy0 ^ hz1) % size;
        const unsigned o2 = (ix ^ hy1 ^ hz0) % size,      o3 = (ix ^ hy1 ^ hz1) % size;
        const unsigned o4 = ((ix+1u) ^ hy0 ^ hz0) % size, o5 = ((ix+1u) ^ hy0 ^ hz1) % size;
        const unsigned o6 = ((ix+1u) ^ hy1 ^ hz0) % size, o7 = ((ix+1u) ^ hy1 ^ hz1) % size;
        const float* tab = codebook + (unsigned)l * CB_STRIDE;
        const float wx1 = frx, wx0 = 1.0f - frx;
        const float wy1 = fry, wy0 = 1.0f - fry;
        const float wz1 = frz, wz0 = 1.0f - frz;
        const float w00 = wy0*wz0, w01 = wy0*wz1, w10 = wy1*wz0, w11 = wy1*wz1;
        acc += wx0 * (tab[o0]*w00 + tab[o1]*w01 + tab[o2]*w10 + tab[o3]*w11)
             + wx1 * (tab[o4]*w00 + tab[o5]*w01 + tab[o6]*w10 + tab[o7]*w11);
    }
    out[i] = acc;
}

extern "C" void kernel_launch(void* const* d_in, const int* in_sizes, int n_in,
                              void* d_out, int out_size, void* d_ws, size_t ws_size,
                              hipStream_t stream)
{
    const float* pts      = (const float*)d_in[0];
    const float* codebook = (const float*)d_in[1];
    float* out            = (float*)d_out;
    const int n = in_sizes[0] / 3;

    // numpy-matching LOD7 resolution (16*b^7 sits ~1e-12 from 512.0)
    const double b = exp((log(512.0) - log(16.0)) / 7.0);
    const int res7 = (int)(1.0 + floor(16.0 * pow(b, 7.0)));

    const bool use_ws = (d_ws != nullptr) && (ws_size >= WS_NEED_BYTES);
    const int blocks = (n + 1023) / 1024;

    if (use_ws) {
        unsigned short* ws = (unsigned short*)d_ws;
        hipLaunchKernelGGL(HashGrid_convert_kernel, dim3(512, 6), dim3(1024),
                           0, stream, codebook, ws);
        hipLaunchKernelGGL(HashGrid_88278757802387_kernel, dim3(blocks), dim3(1024),
                           0, stream, pts, codebook, ws, out, n, res7);
    } else {
        hipLaunchKernelGGL(HashGrid_fallback_kernel, dim3(blocks), dim3(1024),
                           0, stream, pts, codebook, out, n, res7);
    }
}

// Round 5
// 406.477 us; speedup vs baseline: 1.1027x; 1.0032x over previous
//
#include <hip/hip_runtime.h>
#include <math.h>

// HashGrid: 8 LODs, hashed trilinear interp, 1 feature/entry, summed over LODs.
// LODS  = [17, 27, 44, 71, 116, 191, 313, res7(host-computed, 512 or 513)]
// SIZES = [4913, 19683, 85184, 357911, 2^19, 2^19, 2^19, 2^19]
// codebook layout: [8][524288][1] float32.
//
// R5: force the deep gather pipeline to actually exist.
//   - __launch_bounds__(1024, 4): VGPR cap 128 (R2-R4's (1024,8) pinned the
//     allocator at 32 VGPRs -> ~6 outstanding gathers -> latency-bound).
//   - Compute ALL 48 global indices, issue ALL 48 u16 gathers, then run the
//     LDS LODs + their math under the in-flight latency, then consume.
//   - 16 waves/CU x 48 outstanding = 768 lane-requests in flight per CU.

static constexpr unsigned CB_STRIDE = 524288u;
static constexpr int S0 = 4913;    // 17^3
static constexpr int S1 = 19683;   // 27^3
// ws (bf16) element offsets for LOD2..7
static constexpr int WO2 = 0;        // 85184
static constexpr int WO3 = 85184;    // 357911
static constexpr int WO4 = 443104;   // 524288 (aligned up)
static constexpr int WO5 = 967392;
static constexpr int WO6 = 1491680;
static constexpr int WO7 = 2015968;
static constexpr size_t WS_NEED_BYTES = 2540256u * 2u;  // 5.08 MB

__device__ __forceinline__ unsigned short f32_to_bf16_rne(float f) {
    unsigned u = __float_as_uint(f);
    u = (u + 0x7FFFu + ((u >> 16) & 1u)) >> 16;
    return (unsigned short)u;
}
__device__ __forceinline__ float bf16_to_f32(unsigned short s) {
    return __uint_as_float(((unsigned)s) << 16);
}

struct I8 { unsigned a0, a1, a2, a3, a4, a5, a6, a7; };
struct R8 { unsigned short v0, v1, v2, v3, v4, v5, v6, v7; };
struct W3 { float x, y, z; };

template <unsigned SIZE, bool POW2>
__device__ __forceinline__ I8 idx8(float p01x, float p01y, float p01z, int res, W3& fr)
{
    const float rm1 = (float)(res - 1);
    float xx = p01x * rm1, yy = p01y * rm1, zz = p01z * rm1;
    const float cmax = (float)(res - 2);
    float fx = fminf(fmaxf(floorf(xx), 0.0f), cmax);
    float fy = fminf(fmaxf(floorf(yy), 0.0f), cmax);
    float fz = fminf(fmaxf(floorf(zz), 0.0f), cmax);
    fr.x = xx - fx; fr.y = yy - fy; fr.z = zz - fz;
    const unsigned ix = (unsigned)(int)fx;
    const unsigned iy = (unsigned)(int)fy;
    const unsigned iz = (unsigned)(int)fz;

    const unsigned hx0 = ix;                  // PRIME0 = 1
    const unsigned hx1 = ix + 1u;
    const unsigned hy0 = iy * 2654435761u;
    const unsigned hy1 = hy0 + 2654435761u;
    const unsigned hz0 = iz * 805459861u;
    const unsigned hz1 = hz0 + 805459861u;

    unsigned v0 = hx0 ^ hy0 ^ hz0;
    unsigned v1 = hx0 ^ hy0 ^ hz1;
    unsigned v2 = hx0 ^ hy1 ^ hz0;
    unsigned v3 = hx0 ^ hy1 ^ hz1;
    unsigned v4 = hx1 ^ hy0 ^ hz0;
    unsigned v5 = hx1 ^ hy0 ^ hz1;
    unsigned v6 = hx1 ^ hy1 ^ hz0;
    unsigned v7 = hx1 ^ hy1 ^ hz1;

    if (POW2) {
        const unsigned m = SIZE - 1u;
        v0 &= m; v1 &= m; v2 &= m; v3 &= m; v4 &= m; v5 &= m; v6 &= m; v7 &= m;
    } else {
        v0 %= SIZE; v1 %= SIZE; v2 %= SIZE; v3 %= SIZE;
        v4 %= SIZE; v5 %= SIZE; v6 %= SIZE; v7 %= SIZE;
    }
    I8 o; o.a0 = v0; o.a1 = v1; o.a2 = v2; o.a3 = v3;
          o.a4 = v4; o.a5 = v5; o.a6 = v6; o.a7 = v7;
    return o;
}

__device__ __forceinline__ R8 gather8(const unsigned short* __restrict__ t, I8 o)
{
    R8 r;
    r.v0 = t[o.a0]; r.v1 = t[o.a1]; r.v2 = t[o.a2]; r.v3 = t[o.a3];
    r.v4 = t[o.a4]; r.v5 = t[o.a5]; r.v6 = t[o.a6]; r.v7 = t[o.a7];
    return r;
}

__device__ __forceinline__ float acc8(R8 r, W3 f)
{
    const float wx1 = f.x, wx0 = 1.0f - f.x;
    const float wy1 = f.y, wy0 = 1.0f - f.y;
    const float wz1 = f.z, wz0 = 1.0f - f.z;
    const float w00 = wy0 * wz0, w01 = wy0 * wz1;
    const float w10 = wy1 * wz0, w11 = wy1 * wz1;
    const float sx0 = bf16_to_f32(r.v0) * w00 + bf16_to_f32(r.v1) * w01
                    + bf16_to_f32(r.v2) * w10 + bf16_to_f32(r.v3) * w11;
    const float sx1 = bf16_to_f32(r.v4) * w00 + bf16_to_f32(r.v5) * w01
                    + bf16_to_f32(r.v6) * w10 + bf16_to_f32(r.v7) * w11;
    return wx0 * sx0 + wx1 * sx1;
}

// prep: convert LOD2..7 table prefixes to bf16 in ws
__global__ __launch_bounds__(1024)
void HashGrid_convert_kernel(const float* __restrict__ codebook,
                             unsigned short* __restrict__ ws)
{
    const int lod = blockIdx.y;  // 0..5 -> LOD2..7
    const int sizes[6] = {85184, 357911, 524288, 524288, 524288, 524288};
    const int offs[6]  = {WO2, WO3, WO4, WO5, WO6, WO7};
    const int idx = blockIdx.x * 1024 + threadIdx.x;
    if (idx < sizes[lod])
        ws[offs[lod] + idx] = f32_to_bf16_rne(codebook[(unsigned)(lod + 2) * CB_STRIDE + idx]);
}

__global__ __launch_bounds__(1024, 4)
void HashGrid_88278757802387_kernel(const float* __restrict__ pts,
                                    const float* __restrict__ codebook,
                                    const unsigned short* __restrict__ ws,
                                    float* __restrict__ out,
                                    int n, int res7)
{
    __shared__ unsigned short sm[S0 + S1];  // 49.2 KB
    for (int j = threadIdx.x; j < S0 + S1; j += 1024)
        sm[j] = f32_to_bf16_rne(j < S0 ? codebook[j] : codebook[CB_STRIDE + (j - S0)]);
    __syncthreads();

    const int i = blockIdx.x * 1024 + threadIdx.x;
    if (i >= n) return;

    const float p01x = pts[3 * i + 0] * 0.5f + 0.5f;
    const float p01y = pts[3 * i + 1] * 0.5f + 0.5f;
    const float p01z = pts[3 * i + 2] * 0.5f + 0.5f;

    // ---- compute all 48 global indices ----
    W3 fA, fB, fC, fD, fE, fF, fL0, fL1;
    I8 oA = idx8<85184u,  false>(p01x, p01y, p01z, 44,   fA);
    I8 oB = idx8<357911u, false>(p01x, p01y, p01z, 71,   fB);
    I8 oC = idx8<524288u, true >(p01x, p01y, p01z, 116,  fC);
    I8 oD = idx8<524288u, true >(p01x, p01y, p01z, 191,  fD);
    I8 oE = idx8<524288u, true >(p01x, p01y, p01z, 313,  fE);
    I8 oF = idx8<524288u, true >(p01x, p01y, p01z, res7, fF);

    // ---- issue all 48 gathers back-to-back ----
    R8 rA = gather8(ws + WO2, oA);
    R8 rB = gather8(ws + WO3, oB);
    R8 rC = gather8(ws + WO4, oC);
    R8 rD = gather8(ws + WO5, oD);
    R8 rE = gather8(ws + WO6, oE);
    R8 rF = gather8(ws + WO7, oF);

    // ---- LDS LODs 0/1 under the in-flight global latency ----
    I8 oL0 = idx8<4913u,  false>(p01x, p01y, p01z, 17, fL0);
    I8 oL1 = idx8<19683u, false>(p01x, p01y, p01z, 27, fL1);
    R8 rL0 = gather8(sm, oL0);
    R8 rL1 = gather8(sm + S0, oL1);
    float acc = acc8(rL0, fL0) + acc8(rL1, fL1);

    // ---- consume in issue order ----
    acc += acc8(rA, fA);
    acc += acc8(rB, fB);
    acc += acc8(rC, fC);
    acc += acc8(rD, fD);
    acc += acc8(rE, fE);
    acc += acc8(rF, fF);

    out[i] = acc;
}

// fallback (no ws): per-LOD f32 path
__global__ __launch_bounds__(1024, 4)
void HashGrid_fallback_kernel(const float* __restrict__ pts,
                              const float* __restrict__ codebook,
                              float* __restrict__ out,
                              int n, int res7)
{
    const int i = blockIdx.x * 1024 + threadIdx.x;
    if (i >= n) return;
    const float p01x = pts[3 * i + 0] * 0.5f + 0.5f;
    const float p01y = pts[3 * i + 1] * 0.5f + 0.5f;
    const float p01z = pts[3 * i + 2] * 0.5f + 0.5f;
    float acc = 0.0f;
    const int      reslist[8]  = {17, 27, 44, 71, 116, 191, 313, res7};
    const unsigned sizelist[8] = {4913u, 19683u, 85184u, 357911u, 524288u, 524288u, 524288u, 524288u};
    for (int l = 0; l < 8; ++l) {
        const int res = reslist[l];
        const unsigned size = sizelist[l];
        const float rm1 = (float)(res - 1);
        float xx = p01x * rm1, yy = p01y * rm1, zz = p01z * rm1;
        float fx = fminf(fmaxf(floorf(xx), 0.0f), (float)(res - 2));
        float fy = fminf(fmaxf(floorf(yy), 0.0f), (float)(res - 2));
        float fz = fminf(fmaxf(floorf(zz), 0.0f), (float)(res - 2));
        const float frx = xx - fx, fry = yy - fy, frz = zz - fz;
        const unsigned ix = (unsigned)(int)fx, iy = (unsigned)(int)fy, iz = (unsigned)(int)fz;
        const unsigned hy0 = iy * 2654435761u, hy1 = hy0 + 2654435761u;
        const unsigned hz0 = iz * 805459861u,  hz1 = hz0 + 805459861u;
        const unsigned o0 = (ix ^ hy0 ^ hz0) % size,      o1 = (ix ^ hy0 ^ hz1) % size;
        const unsigned o2 = (ix ^ hy1 ^ hz0) % size,      o3 = (ix ^ hy1 ^ hz1) % size;
        const unsigned o4 = ((ix+1u) ^ hy0 ^ hz0) % size, o5 = ((ix+1u) ^ hy0 ^ hz1) % size;
        const unsigned o6 = ((ix+1u) ^ hy1 ^ hz0) % size, o7 = ((ix+1u) ^ hy1 ^ hz1) % size;
        const float* tab = codebook + (unsigned)l * CB_STRIDE;
        const float wx1 = frx, wx0 = 1.0f - frx;
        const float wy1 = fry, wy0 = 1.0f - fry;
        const float wz1 = frz, wz0 = 1.0f - frz;
        const float w00 = wy0*wz0, w01 = wy0*wz1, w10 = wy1*wz0, w11 = wy1*wz1;
        acc += wx0 * (tab[o0]*w00 + tab[o1]*w01 + tab[o2]*w10 + tab[o3]*w11)
             + wx1 * (tab[o4]*w00 + tab[o5]*w01 + tab[o6]*w10 + tab[o7]*w11);
    }
    out[i] = acc;
}

extern "C" void kernel_launch(void* const* d_in, const int* in_sizes, int n_in,
                              void* d_out, int out_size, void* d_ws, size_t ws_size,
                              hipStream_t stream)
{
    const float* pts      = (const float*)d_in[0];
    const float* codebook = (const float*)d_in[1];
    float* out            = (float*)d_out;
    const int n = in_sizes[0] / 3;

    // numpy-matching LOD7 resolution (16*b^7 sits ~1e-12 from 512.0)
    const double b = exp((log(512.0) - log(16.0)) / 7.0);
    const int res7 = (int)(1.0 + floor(16.0 * pow(b, 7.0)));

    const bool use_ws = (d_ws != nullptr) && (ws_size >= WS_NEED_BYTES);
    const int blocks = (n + 1023) / 1024;

    if (use_ws) {
        unsigned short* ws = (unsigned short*)d_ws;
        hipLaunchKernelGGL(HashGrid_convert_kernel, dim3(512, 6), dim3(1024),
                           0, stream, codebook, ws);
        hipLaunchKernelGGL(HashGrid_88278757802387_kernel, dim3(blocks), dim3(1024),
                           0, stream, pts, codebook, ws, out, n, res7);
    } else {
        hipLaunchKernelGGL(HashGrid_fallback_kernel, dim3(blocks), dim3(1024),
                           0, stream, pts, codebook, out, n, res7);
    }
}